// Round 4
// baseline (135.644 us; speedup 1.0000x reference)
//
#include <hip/hip_runtime.h>

constexpr int Cc   = 224;            // channels
constexpr int Tt   = 224;            // time steps
constexpr int TT   = 32;             // time tile
constexpr int NT   = Tt / TT;        // 7
constexpr int ROWS = 236;            // row r <-> channel r-6; rows 0..5,230..235 zero halo
constexpr int BUFW = ROWS * TT;      // 7552 words per buffer
constexpr int BDIM = 256;
constexpr int CPG  = 28;             // channels per thread in phase A (8 groups x 32 t)

// async 16B-per-lane global->LDS; dest = wave-uniform base + lane*16
#define GLDS16(src, dst) __builtin_amdgcn_global_load_lds( \
    (const __attribute__((address_space(1))) unsigned int*)(src), \
    (__attribute__((address_space(3))) unsigned int*)(dst), 16, 0, 0)

// x-tile layout: LINEAR  word(row,t) = row*32 + t   (phase-A b32 reads: 2-way, free)
// I/spike layout (overlaid on dead x rows 6..229 after phase A):
//   word(row,t) = row*32 + ((tq ^ (row&7))<<2) + (t&3)   -> balanced b128 row reads

__global__ __launch_bounds__(BDIM, 2)
void cgss_snn_kernel(const float* __restrict__ x,
                     const float* __restrict__ wp,
                     float* __restrict__ out)
{
    __shared__ float lds[2 * BUFW];   // 60416 B -> 2 blocks/CU

    const int tid = threadIdx.x;
    const int w   = tid >> 6;         // wave 0..3
    const int l   = tid & 63;
    const int b   = blockIdx.x;
    const long long bofs = (long long)b * (Cc * Tt);
    const float* xb = x + bofs;
    float*       ob = out + bofs;

    // ---- zero halo rows (0..5, 230..235) in both buffers, once ----
    if (tid < 192) {
        int bufi = tid / 96;
        int q    = tid - 96 * bufi;
        int rr   = q >> 3;
        int slot = q & 7;
        int row  = (rr < 6) ? rr : (224 + rr);
        float4 z = make_float4(0.f, 0.f, 0.f, 0.f);
        *reinterpret_cast<float4*>(&lds[bufi * BUFW + row * 32 + slot * 4]) = z;
    }

    // ---- async stage: 28 chunks (rows 6..229), 7 per wave, linear layout ----
    const int srow = l >> 3;          // row within 8-row chunk
    const int scol = l & 7;           // t-quad
    auto stage = [&](int bufi, int t0) {
        float* base = &lds[bufi * BUFW];
#pragma unroll
        for (int i = 0; i < 7; ++i) {
            int j = 7 * w + i;
            const float* src = xb + (8 * j + srow) * Tt + t0 + scol * 4; // channel = 8j+srow
            GLDS16(src, &base[(6 + 8 * j) * 32]);
        }
    };

    stage(0, 0);   // tile 0 in flight while we compute the gaussian kernel

    // ---- gaussian kernel (arithmetic identical to verified rounds 1-3) ----
    float kr[13];
    {
        float wv = wp[0];
        float wc = fminf(fmaxf(wv, 0.4f), 10.0f);
        float norm = 0.0f;
        const float step = 120.0f / 129.0f;
        for (int j = 0; j < 130; ++j) {
            float r = -60.0f + (float)j * step;
            float z = r / wc;
            norm += expf(-0.5f * z * z);
        }
        for (int i = 0; i < 13; ++i) {
            float r = (float)(i - 6);
            float z = r / wc;
            kr[i] = expf(-0.5f * z * z) / norm;
        }
    }

    const int g     = tid >> 5;       // phase-A group 0..7
    const int l5    = tid & 31;       // phase-A time lane
    const int rowA0 = CPG * g;        // first read row (= first channel - 6 + 6)
    const int rowB  = tid + 6;        // phase-B I row (tid < 224)
    const int pB    = rowB & 7;

    float mem = 0.0f, rstv = 0.0f;    // LIF state (phase-B threads), across tiles
    int bufc = 0;

    asm volatile("s_waitcnt vmcnt(0)" ::: "memory");
    __syncthreads();                  // buf0 staged for all waves

    for (int tile = 0; tile < NT; ++tile) {
        const int t0 = tile * TT;
        if (tile < NT - 1) stage(bufc ^ 1, t0 + TT);   // overlap next-tile HBM

        // ---- phase A: sliding-window conv, lane = t ----
        float acc[CPG], ctr[CPG];
        {
            const float* sb = &lds[bufc * BUFW] + rowA0 * 32 + l5;
#pragma unroll
            for (int j = 0; j < CPG; ++j) acc[j] = 0.0f;
#pragma unroll
            for (int r = 0; r < CPG + 12; ++r) {        // 40 b32 reads, each row once
                float xv = sb[r * 32];
#pragma unroll
                for (int j = 0; j < CPG; ++j) {
                    int i = r - j;                      // tap index (ascending = ref order)
                    if (i == 6) ctr[j] = xv;            // center value x[c][t]
                    if (i >= 0 && i < 13) acc[j] += kr[i] * xv;
                }
            }
#pragma unroll
            for (int j = 0; j < CPG; ++j) {             // I = x - relu(x - mean)
                float xv = ctr[j];
                float d  = xv - acc[j];
                float rl = d > 0.0f ? d : 0.0f;
                acc[j]   = xv - rl;                     // acc now holds I
            }
        }
        __syncthreads();   // bar1: all x reads done -> safe to overwrite with I

        // ---- writeback I into the dead x rows (swizzled) ----
        {
            float* sb = &lds[bufc * BUFW];
            const int q = l5 >> 2, lo = l5 & 3;
#pragma unroll
            for (int j = 0; j < CPG; ++j) {
                int row = rowA0 + 6 + j;
                sb[row * 32 + ((q ^ (row & 7)) << 2) + lo] = acc[j];
            }
        }
        __syncthreads();   // bar2: I visible

        // ---- phase B: LIF along t, lane = channel ----
        if (tid < Cc) {
            char* sb = (char*)&lds[bufc * BUFW] + rowB * 128;
#pragma unroll
            for (int tq = 0; tq < 8; ++tq) {
                char* p = sb + ((tq ^ pB) << 4);
                float4 v = *reinterpret_cast<const float4*>(p);
                float4 s4;
                float* vv = (float*)&v;
                float* ss = (float*)&s4;
#pragma unroll
                for (int s = 0; s < 4; ++s) {
                    mem = 0.97f * mem + vv[s] - rstv;
                    bool sp = mem > 1.0f;
                    rstv = sp ? 1.0f : 0.0f;
                    ss[s] = sp ? 1.0f : 0.0f;
                }
                *reinterpret_cast<float4*>(p) = s4;     // spikes over own row
            }
        }
        __syncthreads();   // bar3: spikes visible

        // ---- coalesced store: full 128B line coverage per instruction ----
        {
            const char* sb = (const char*)&lds[bufc * BUFW];
            const int s = l & 7;
#pragma unroll
            for (int i = 0; i < 7; ++i) {
                int row = 6 + 8 * (7 * w + i) + (l >> 3);
                float4 v = *reinterpret_cast<const float4*>(
                    sb + row * 128 + ((s ^ (row & 7)) << 4));
                *reinterpret_cast<float4*>(
                    &ob[(long long)(row - 6) * Tt + t0 + 4 * s]) = v;
            }
        }

        // counted wait: retire our 7 GLDS (don't drain this tile's 7 stores)
        asm volatile("s_waitcnt vmcnt(7)" ::: "memory");
        __syncthreads();   // bar4: safe to restage into this buffer next tile
        bufc ^= 1;
    }
}

extern "C" void kernel_launch(void* const* d_in, const int* in_sizes, int n_in,
                              void* d_out, int out_size, void* d_ws, size_t ws_size,
                              hipStream_t stream)
{
    const float* x  = (const float*)d_in[0];
    const float* w  = (const float*)d_in[1];
    float* out      = (float*)d_out;
    const int B = in_sizes[0] / (Cc * Tt);   // 512
    cgss_snn_kernel<<<B, BDIM, 0, stream>>>(x, w, out);
}

// Round 5
// 89.176 us; speedup vs baseline: 1.5211x; 1.5211x over previous
//
#include <hip/hip_runtime.h>

constexpr int Cc   = 224;            // channels
constexpr int Tt   = 224;            // time steps
constexpr int TT   = 32;             // time tile
constexpr int NT   = Tt / TT;        // 7
constexpr int LDW  = 36;             // words per LDS row (144 B) -> b128 reads bank-balanced
constexpr int ROWS = 236;            // row r <-> channel r-6; rows 0..5,230..235 zero halo
constexpr int BUFW = ROWS * LDW;     // 8496 words per buffer
constexpr int BDIM = 256;

__global__ __launch_bounds__(BDIM, 2)
void cgss_snn_kernel(const float* __restrict__ x,
                     const float* __restrict__ wp,
                     float* __restrict__ out)
{
    __shared__ float lds[2 * BUFW];  // 67968 B -> 2 blocks/CU (135.9 of 160 KiB)

    const int tid = threadIdx.x;
    const int w   = tid >> 6;        // wave 0..3
    const int l   = tid & 63;
    const long long bofs = (long long)blockIdx.x * (Cc * Tt);
    const float* xb = x + bofs;
    float*       ob = out + bofs;

    // ---- zero halo rows (0..5, 230..235) in both buffers, once ----
    if (tid < 192) {
        int bufi = tid / 96;
        int q    = tid - 96 * bufi;
        int rr   = q >> 3;                       // 0..11
        int slot = q & 7;
        int row  = (rr < 6) ? rr : (224 + rr);   // 0..5, 230..235
        *reinterpret_cast<float4*>(&lds[bufi * BUFW + row * LDW + slot * 4]) =
            make_float4(0.f, 0.f, 0.f, 0.f);
    }

    // stage/store lane mapping: 7 chunks of 8 channel-rows per wave
    const int srow = l >> 3;         // row within 8-row chunk
    const int stq  = l & 7;          // t-quad
    const int rowbase = 56 * w + srow;

    // ---- issue tile-0 loads (latency hidden under gaussian-kernel math) ----
    float4 vst[7];
#pragma unroll
    for (int i = 0; i < 7; ++i)
        vst[i] = *reinterpret_cast<const float4*>(
            xb + (rowbase + 8 * i) * Tt + 4 * stq);

    // ---- gaussian kernel (arithmetic identical to verified rounds 1-4) ----
    float kr[13];
    {
        float wv = wp[0];
        float wc = fminf(fmaxf(wv, 0.4f), 10.0f);
        float norm = 0.0f;
        const float step = 120.0f / 129.0f;
        for (int j = 0; j < 130; ++j) {
            float r = -60.0f + (float)j * step;
            float z = r / wc;
            norm += expf(-0.5f * z * z);
        }
        for (int i = 0; i < 13; ++i) {
            float r = (float)(i - 6);
            float z = r / wc;
            kr[i] = expf(-0.5f * z * z) / norm;
        }
    }

    // ---- write tile-0 into buf0; issue tile-1 loads ----
#pragma unroll
    for (int i = 0; i < 7; ++i)
        *reinterpret_cast<float4*>(
            &lds[(rowbase + 8 * i + 6) * LDW + 4 * stq]) = vst[i];
#pragma unroll
    for (int i = 0; i < 7; ++i)
        vst[i] = *reinterpret_cast<const float4*>(
            xb + (rowbase + 8 * i) * Tt + TT + 4 * stq);

    asm volatile("s_waitcnt lgkmcnt(0)" ::: "memory");
    __builtin_amdgcn_s_barrier();
    __builtin_amdgcn_sched_barrier(0);

    float mem = 0.f, rstv = 0.f;     // LIF state, carried across tiles
    int bufc = 0;

#pragma unroll 1
    for (int tile = 0; tile < NT; ++tile) {
        const int t0 = tile * TT;
        float* cur = &lds[bufc * BUFW];
        float* nxt = &lds[(bufc ^ 1) * BUFW];

        // ---- conv + LIF: 13 immediate-offset ds_read_b128 per quad ----
        unsigned m = 0;
        if (tid < Cc) {
            const float* base = cur + tid * LDW;   // rows tid..tid+12
#pragma unroll
            for (int tq = 0; tq < 8; ++tq) {
                float4 v[13];
#pragma unroll
                for (int k = 0; k < 13; ++k)
                    v[k] = *reinterpret_cast<const float4*>(base + k * LDW + 4 * tq);
                float4 acc = make_float4(0.f, 0.f, 0.f, 0.f);
#pragma unroll
                for (int k = 0; k < 13; ++k) {
                    float kk = kr[k];
                    acc.x += kk * v[k].x;  acc.y += kk * v[k].y;
                    acc.z += kk * v[k].z;  acc.w += kk * v[k].w;
                }
                const float* xv = (const float*)&v[6];   // center = own channel
                const float* av = (const float*)&acc;
#pragma unroll
                for (int s = 0; s < 4; ++s) {
                    float d  = xv[s] - av[s];
                    float rl = d > 0.0f ? d : 0.0f;
                    float I  = xv[s] - rl;               // I = x - relu(x - mean)
                    mem = 0.97f * mem + I - rstv;
                    bool sp = mem > 1.0f;
                    rstv = sp ? 1.0f : 0.0f;
                    m |= sp ? (1u << (4 * tq + s)) : 0u;
                }
            }
        }

        asm volatile("s_waitcnt lgkmcnt(0)" ::: "memory");
        __builtin_amdgcn_s_barrier();        // bar1: all conv reads retired
        __builtin_amdgcn_sched_barrier(0);

        // ---- expand spikes into dead cur rows ----
        if (tid < Cc) {
            float* sp = cur + (tid + 6) * LDW;
#pragma unroll
            for (int tq = 0; tq < 8; ++tq) {
                float4 s4;
                s4.x = (m >> (4 * tq + 0)) & 1 ? 1.0f : 0.0f;
                s4.y = (m >> (4 * tq + 1)) & 1 ? 1.0f : 0.0f;
                s4.z = (m >> (4 * tq + 2)) & 1 ? 1.0f : 0.0f;
                s4.w = (m >> (4 * tq + 3)) & 1 ? 1.0f : 0.0f;
                *reinterpret_cast<float4*>(sp + 4 * tq) = s4;
            }
        }
        // ---- write staged next-tile x into nxt (T14 late-write) ----
        if (tile < NT - 1) {
#pragma unroll
            for (int i = 0; i < 7; ++i)
                *reinterpret_cast<float4*>(
                    &nxt[(rowbase + 8 * i + 6) * LDW + 4 * stq]) = vst[i];
        }
        // ---- issue loads for tile+2 (a full tile of latency cover) ----
        if (tile < NT - 2) {
#pragma unroll
            for (int i = 0; i < 7; ++i)
                vst[i] = *reinterpret_cast<const float4*>(
                    xb + (rowbase + 8 * i) * Tt + t0 + 2 * TT + 4 * stq);
        }

        asm volatile("s_waitcnt lgkmcnt(0)" ::: "memory");
        __builtin_amdgcn_s_barrier();        // bar2: spikes + next-x visible
        __builtin_amdgcn_sched_barrier(0);

        // ---- coalesced store: 8 full 128B lines per instruction ----
#pragma unroll
        for (int i = 0; i < 7; ++i) {
            int cr = rowbase + 8 * i;
            float4 v = *reinterpret_cast<const float4*>(
                &cur[(cr + 6) * LDW + 4 * stq]);
            *reinterpret_cast<float4*>(&ob[(long long)cr * Tt + t0 + 4 * stq]) = v;
        }

        bufc ^= 1;
    }
}

extern "C" void kernel_launch(void* const* d_in, const int* in_sizes, int n_in,
                              void* d_out, int out_size, void* d_ws, size_t ws_size,
                              hipStream_t stream)
{
    const float* x  = (const float*)d_in[0];
    const float* w  = (const float*)d_in[1];
    float* out      = (float*)d_out;
    const int B = in_sizes[0] / (Cc * Tt);   // 512
    cgss_snn_kernel<<<B, BDIM, 0, stream>>>(x, w, out);
}

// Round 6
// 83.805 us; speedup vs baseline: 1.6186x; 1.0641x over previous
//
#include <hip/hip_runtime.h>

constexpr int Cc   = 224;            // channels
constexpr int Tt   = 224;            // time steps
constexpr int TT   = 32;             // time tile
constexpr int NT   = Tt / TT;        // 7
constexpr int LDW  = 36;             // words per LDS row (144 B) -> b128 bank-balanced
constexpr int ROWS = 236;            // row r <-> channel r-6; rows 0..5,230..235 zero halo
constexpr int BUFW = ROWS * LDW;     // 8496 words per buffer
constexpr int BDIM = 256;

__global__ __launch_bounds__(BDIM, 2)
void cgss_snn_kernel(const float* __restrict__ x,
                     const float* __restrict__ wp,
                     float* __restrict__ out)
{
    __shared__ float lds[2 * BUFW];  // 67968 B -> 2 blocks/CU

    const int tid = threadIdx.x;
    const int w   = tid >> 6;        // wave 0..3
    const int l   = tid & 63;
    const long long bofs = (long long)blockIdx.x * (Cc * Tt);
    const float* xb = x + bofs;
    float*       ob = out + bofs;

    // ---- zero halo rows (0..5, 230..235) in both buffers, once ----
    if (tid < 192) {
        int bufi = tid / 96;
        int q    = tid - 96 * bufi;
        int rr   = q >> 3;                       // 0..11
        int slot = q & 7;
        int row  = (rr < 6) ? rr : (224 + rr);   // 0..5, 230..235
        *reinterpret_cast<float4*>(&lds[bufi * BUFW + row * LDW + slot * 4]) =
            make_float4(0.f, 0.f, 0.f, 0.f);
    }

    // stage/store lane mapping: chunk i covers channels rowbase+8i (8 rows x 8 tq)
    const int srow = l >> 3;         // row within 8-row chunk
    const int stq  = l & 7;          // t-quad
    const int rowbase = 56 * w + srow;

    // ---- issue tile-0 loads (latency hidden under gaussian-kernel math) ----
    float4 vst[7];
#pragma unroll
    for (int i = 0; i < 7; ++i)
        vst[i] = *reinterpret_cast<const float4*>(
            xb + (rowbase + 8 * i) * Tt + 4 * stq);

    // ---- gaussian kernel (arithmetic identical to verified rounds 1-5) ----
    float kr[13];
    {
        float wv = wp[0];
        float wc = fminf(fmaxf(wv, 0.4f), 10.0f);
        float norm = 0.0f;
        const float step = 120.0f / 129.0f;
        for (int j = 0; j < 130; ++j) {
            float r = -60.0f + (float)j * step;
            float z = r / wc;
            norm += expf(-0.5f * z * z);
        }
        for (int i = 0; i < 13; ++i) {
            float r = (float)(i - 6);
            float z = r / wc;
            kr[i] = expf(-0.5f * z * z) / norm;
        }
    }

    // ---- write tile-0 into buf0; issue tile-1 loads ----
#pragma unroll
    for (int i = 0; i < 7; ++i)
        *reinterpret_cast<float4*>(
            &lds[(rowbase + 8 * i + 6) * LDW + 4 * stq]) = vst[i];
#pragma unroll
    for (int i = 0; i < 7; ++i)
        vst[i] = *reinterpret_cast<const float4*>(
            xb + (rowbase + 8 * i) * Tt + TT + 4 * stq);

    asm volatile("s_waitcnt lgkmcnt(0)" ::: "memory");
    __builtin_amdgcn_s_barrier();
    __builtin_amdgcn_sched_barrier(0);

    float mem = 0.f, rstv = 0.f;     // LIF state, carried across tiles
    // spike masks, one 32-bit word per tile, kept as a static shift register
    unsigned r0 = 0, r1 = 0, r2 = 0, r3 = 0, r4 = 0, r5 = 0, r6 = 0;
    int bufc = 0;

#pragma unroll 1
    for (int tile = 0; tile < NT; ++tile) {
        float* cur = &lds[bufc * BUFW];
        float* nxt = &lds[(bufc ^ 1) * BUFW];

        // ---- conv + LIF: 13 immediate-offset ds_read_b128 per quad ----
        unsigned m = 0;
        if (tid < Cc) {
            const float* base = cur + tid * LDW;   // rows tid..tid+12
#pragma unroll
            for (int tq = 0; tq < 8; ++tq) {
                float4 v[13];
#pragma unroll
                for (int k = 0; k < 13; ++k)
                    v[k] = *reinterpret_cast<const float4*>(base + k * LDW + 4 * tq);
                float4 acc = make_float4(0.f, 0.f, 0.f, 0.f);
#pragma unroll
                for (int k = 0; k < 13; ++k) {
                    float kk = kr[k];
                    acc.x += kk * v[k].x;  acc.y += kk * v[k].y;
                    acc.z += kk * v[k].z;  acc.w += kk * v[k].w;
                }
                const float* xv = (const float*)&v[6];   // center = own channel
                const float* av = (const float*)&acc;
#pragma unroll
                for (int s = 0; s < 4; ++s) {
                    float d  = xv[s] - av[s];
                    float rl = d > 0.0f ? d : 0.0f;
                    float I  = xv[s] - rl;               // I = x - relu(x - mean)
                    mem = 0.97f * mem + I - rstv;
                    bool sp = mem > 1.0f;
                    rstv = sp ? 1.0f : 0.0f;
                    m |= sp ? (1u << (4 * tq + s)) : 0u;
                }
            }
        }
        // shift register: after 7 tiles r0..r6 = tiles 0..6 (all static indices)
        r0 = r1; r1 = r2; r2 = r3; r3 = r4; r4 = r5; r5 = r6; r6 = m;

        // ---- stage next tile: write regs (tile+1) into nxt, load tile+2 ----
        if (tile < NT - 1) {
#pragma unroll
            for (int i = 0; i < 7; ++i)
                *reinterpret_cast<float4*>(
                    &nxt[(rowbase + 8 * i + 6) * LDW + 4 * stq]) = vst[i];
        }
        if (tile < NT - 2) {
            const float* src = xb + (tile + 2) * TT + 4 * stq;
#pragma unroll
            for (int i = 0; i < 7; ++i)
                vst[i] = *reinterpret_cast<const float4*>(
                    src + (rowbase + 8 * i) * Tt);
        }

        // one barrier per tile: protects cur reads vs next-tile writes into cur
        if (tile < NT - 1) {
            asm volatile("s_waitcnt lgkmcnt(0)" ::: "memory");
            __builtin_amdgcn_s_barrier();
            __builtin_amdgcn_sched_barrier(0);
        }
        bufc ^= 1;
    }

    // ---- pivot masks through buf1 (idle since tile 5; disjoint from tile-6 reads) ----
    unsigned* mw = reinterpret_cast<unsigned*>(&lds[BUFW]);
    if (tid < Cc) {
        const int mb = tid * 9;          // *9: coprime with 32 banks
        mw[mb + 0] = r0; mw[mb + 1] = r1; mw[mb + 2] = r2; mw[mb + 3] = r3;
        mw[mb + 4] = r4; mw[mb + 5] = r5; mw[mb + 6] = r6;
    }
    asm volatile("s_waitcnt lgkmcnt(0)" ::: "memory");
    __builtin_amdgcn_s_barrier();
    __builtin_amdgcn_sched_barrier(0);

    // ---- store: each channel's full 896B row written in 7 back-to-back instrs ----
#pragma unroll 1
    for (int i = 0; i < 7; ++i) {
        const int cr = rowbase + 8 * i;
        float* dst = ob + (long long)cr * Tt + 4 * stq;
        const unsigned* mrow = mw + cr * 9;
#pragma unroll
        for (int k = 0; k < 7; ++k) {
            unsigned mk = mrow[k];                 // broadcast within lane octet
            unsigned rb = mk >> (4 * stq);
            float4 s4;
            s4.x = (rb & 1u) ? 1.0f : 0.0f;
            s4.y = (rb & 2u) ? 1.0f : 0.0f;
            s4.z = (rb & 4u) ? 1.0f : 0.0f;
            s4.w = (rb & 8u) ? 1.0f : 0.0f;
            *reinterpret_cast<float4*>(dst + k * TT) = s4;
        }
    }
}

extern "C" void kernel_launch(void* const* d_in, const int* in_sizes, int n_in,
                              void* d_out, int out_size, void* d_ws, size_t ws_size,
                              hipStream_t stream)
{
    const float* x  = (const float*)d_in[0];
    const float* w  = (const float*)d_in[1];
    float* out      = (float*)d_out;
    const int B = in_sizes[0] / (Cc * Tt);   // 512
    cgss_snn_kernel<<<B, BDIM, 0, stream>>>(x, w, out);
}